// Round 3
// baseline (619.757 us; speedup 1.0000x reference)
//
#include <hip/hip_runtime.h>
#include <hip/hip_bf16.h>

// GPNN_HICO: B=4, N=256, EDGE_F=256, MSG=128, LINK_H=128, ROUNDS=3, CLASSES=600
// Algebra:
//  - only the valid[b] x valid[b] block matters
//  - m_raw is round-invariant
//  - link rounds: e_state @ W_l1 = sig(s)*(mraw @ W_l1) = sig(s)*u  (scalar gate)
//    => precompute u (bf16) once in k_r0; link rounds are elementwise.
// 5 dispatches: detect, prep(zero+pack+nf/cb), r0, linkE, linkF(link+final fused).
// R3 fix: ub is 64 MiB (not 32) -> s_a/s_b moved past 128 MiB (R2 had them
// inside ub's range; k_r0's ub stores corrupted the link scores -> NaN).

#define B_ 4
#define N_ 256
#define EF_ 256
#define M_ 128
#define CL_ 600
#define ADJ_SZ (B_*N_*N_)

typedef __hip_bfloat16 bf16;
typedef short short8 __attribute__((ext_vector_type(8)));
typedef float f32x4 __attribute__((ext_vector_type(4)));
typedef float fvec4 __attribute__((ext_vector_type(4)));

#define MFMA(a,b,c) __builtin_amdgcn_mfma_f32_16x16x32_bf16(a,b,c,0,0,0)

__device__ __forceinline__ float s2f(short s){
  union { unsigned int u; float f; } x; x.u = ((unsigned int)(unsigned short)s) << 16; return x.f;
}
__device__ __forceinline__ bf16 f2b(float f){ return __float2bfloat16(f); }
__device__ __forceinline__ float sigm(float x){ return 1.0f/(1.0f+expf(-x)); }

__device__ __forceinline__ float ldr(const void* p, size_t i, bool bf){
  return bf ? s2f(((const short*)p)[i]) : ((const float*)p)[i];
}
__device__ __forceinline__ void str(void* p, size_t i, float v, bool bf){
  if (bf) ((bf16*)p)[i] = f2b(v);
  else    ((float*)p)[i] = v;
}

// ---- dtype detector: bf16 buffers ~100% sane exponents; fp32-as-u16 ~59% ----
__global__ __launch_bounds__(64)
void k_detect(const unsigned short* ef, int* flag){
  int t = threadIdx.x;
  int cnt = 0;
  for (int j = 0; j < 64; j++){
    unsigned short u = ef[t*64 + j];
    int e = (u >> 7) & 0xFF;
    cnt += (e >= 96 && e <= 144) ? 1 : 0;
  }
  for (int o = 32; o > 0; o >>= 1) cnt += __shfl_down(cnt, o, 64);
  if (t == 0) *flag = (cnt > 3500) ? 1 : 0;
}

// ---- merged prep: zero output | MFMA-pack 3 weights | nf/cb per node ----
// block ranges: [0,nzb) zero ; [nzb,nzb+32) packs (4 units/block) ;
//               [nzb+32, nzb+32+1024) nf/cb (one block per (b,v))
__global__ __launch_bounds__(256)
void k_prep(const void* W_er, const void* W_msg, const void* W_l1,
            const void* nodef, const void* W_nr, const void* b_nr, const void* b_msg,
            bf16* pWer, bf16* pWmsgB, bf16* pWl1,
            float* nf, float* cb,
            void* out, int out_size, const int* dflag)
{
  __shared__ float xs[EF_];
  __shared__ float pp[2][M_];
  __shared__ float nfs[M_];
  bool bf = (*dflag != 0);
  int nzb = (out_size + 255) >> 8;
  int blk = blockIdx.x;
  int t = threadIdx.x;
  if (blk < nzb){
    int i = blk*256 + t;
    if (i < out_size) str(out, i, 0.f, bf);
    return;
  }
  blk -= nzb;
  if (blk < 32){
    // MFMA B-fragment pack: dst[(u2*64+lane)*8+j] = src[(kk*32+(lane>>4)*8+j)*128 + nt*16+(lane&15)]
    int unit = blk*4 + (t>>6);
    int lane = t & 63;
    const void* src; bf16* dst; int u2;
    if (unit < 64){ src = W_er; dst = pWer; u2 = unit; }            // K=256,N=128
    else if (unit < 96){                                            // K=128,N=128
      src = bf ? (const void*)((const short*)W_msg + 128*M_)
               : (const void*)((const float*)W_msg + 128*M_);
      dst = pWmsgB; u2 = unit - 64;
    } else { src = W_l1; dst = pWl1; u2 = unit - 96; }              // K=128,N=128
    int kk = u2 >> 3, nt = u2 & 7;
    int k0 = kk*32 + (lane>>4)*8;
    int n  = nt*16 + (lane&15);
    size_t dbase = ((size_t)u2*64 + lane)*8;
    #pragma unroll
    for (int j=0;j<8;j++)
      dst[dbase+j] = f2b(ldr(src, (size_t)(k0+j)*128 + n, bf));
    return;
  }
  blk -= 32;
  if (blk >= 1024) return;
  // nf[b,v,:] = node @ W_nr + b_nr ; cb[b,v,:] = b_msg + nf @ W_msg[0:128,:]
  int b = blk >> 8, v = blk & 255;
  int f = t & 127, h = t >> 7;
  size_t xrow = ((size_t)(b*N_)+v)*EF_;
  xs[t] = ldr(nodef, xrow + t, bf);
  __syncthreads();
  float acc = 0.f;
  for (int k = h*128; k < h*128+128; k++)
    acc += xs[k]*ldr(W_nr, (size_t)k*M_ + f, bf);
  pp[h][f] = acc;
  __syncthreads();
  if (h == 0){
    float nv = pp[0][f] + pp[1][f] + ldr(b_nr, f, bf);
    nf[((size_t)(b*N_)+v)*M_ + f] = nv;
    nfs[f] = nv;
  }
  __syncthreads();
  float acc2 = 0.f;
  for (int k = h*64; k < h*64+64; k++)
    acc2 += nfs[k]*ldr(W_msg, (size_t)k*M_ + f, bf);
  pp[h][f] = acc2;
  __syncthreads();
  if (h == 0)
    cb[((size_t)(b*N_)+v)*M_ + f] = pp[0][f] + pp[1][f] + ldr(b_msg, f, bf);
}

// Fused round 0 per (b, i, 32-w tile): MFMA GEMMs.
//   ef   = edge @ W_er + b_er
//   mraw = relu(cb[b,w] + ef @ W_msg[128:,:])   (bf16 to global + LDS)
//   s0   = relu(ef @ W_l1 + b_l1) @ W_l2 + b_l2
//   u    = mraw @ W_l1                           (bf16 to global)
__global__ __launch_bounds__(256)
void k_r0(const void* edgef, const bf16* pWer, const void* b_er,
          const bf16* pWmsgB, const float* cb, const bf16* pWl1,
          const void* b_l1, const void* W_l2, const void* b_l2,
          const int* hn, const int* on, bf16* mraw, bf16* ub, float* s0,
          const int* dflag)
{
  bool bf = (*dflag != 0);
  int b = blockIdx.z, i = blockIdx.y, w0 = blockIdx.x*32;
  int valid = hn[b] + on[b];
  if (i >= valid || w0 >= valid) return;
  int t = threadIdx.x;
  __shared__ __attribute__((aligned(16))) bf16 EfsB[32][136];
  __shared__ __attribute__((aligned(16))) bf16 MrB[32][136];
  __shared__ __attribute__((aligned(16))) char uni[32*264*2]; // Xs bf16[32][264] | hls f32[32][132]
  bf16  (*Xs)[264]  = (bf16(*)[264])uni;
  float (*hls)[132] = (float(*)[132])uni;

  // stage edge rows [32][256]
  {
    int j = t>>3, c = (t&7)*32;
    size_t g = (((size_t)(b*N_)+i)*N_ + (size_t)(w0+j))*EF_ + c;
    if (bf){
      const short8* src = (const short8*)((const short*)edgef + g);
      short8* dst = (short8*)&Xs[j][c];
      #pragma unroll
      for (int q=0;q<4;q++) dst[q] = src[q];
    } else {
      const fvec4* src = (const fvec4*)((const float*)edgef + g);
      #pragma unroll
      for (int q=0;q<8;q++){
        fvec4 v = src[q];
        #pragma unroll
        for (int e=0;e<4;e++) Xs[j][c+q*4+e] = f2b(v[e]);
      }
    }
  }
  __syncthreads();

  int lane = t & 63, wv = t >> 6;
  int r0 = (wv&1)*16;
  int c0h = wv >> 1;               // column half (0/1), 64 cols each
  int mA = r0 + (lane&15);
  int kq = (lane>>4)*8;
  int qrow = r0 + (lane>>4)*4;

  f32x4 z4 = {0.f,0.f,0.f,0.f};
  f32x4 acc[4] = {z4,z4,z4,z4};
  for (int kk=0;kk<8;kk++){
    short8 a = *(const short8*)&Xs[mA][kk*32 + kq];
    #pragma unroll
    for (int nt=0;nt<4;nt++){
      int gnt = c0h*4 + nt;
      short8 bb = *(const short8*)(pWer + (((size_t)kk*8 + gnt)*64 + lane)*8);
      acc[nt] = MFMA(a, bb, acc[nt]);
    }
  }
  // ef -> LDS bf16 (with bias)
  #pragma unroll
  for (int nt=0;nt<4;nt++){
    int col = c0h*64 + nt*16 + (lane&15);
    float be = ldr(b_er, col, bf);
    #pragma unroll
    for (int r=0;r<4;r++)
      EfsB[qrow+r][col] = f2b(acc[nt][r] + be);
  }
  __syncthreads();

  // GEMM2 (mraw) + GEMM3 (hl), shared A-frags, K=128
  f32x4 am[4] = {z4,z4,z4,z4};
  f32x4 ah[4] = {z4,z4,z4,z4};
  for (int kk=0;kk<4;kk++){
    short8 a = *(const short8*)&EfsB[mA][kk*32 + kq];
    #pragma unroll
    for (int nt=0;nt<4;nt++){
      int gnt = c0h*4 + nt;
      size_t off = (((size_t)kk*8 + gnt)*64 + lane)*8;
      short8 b1 = *(const short8*)(pWmsgB + off);
      am[nt] = MFMA(a, b1, am[nt]);
      short8 b2 = *(const short8*)(pWl1 + off);
      ah[nt] = MFMA(a, b2, ah[nt]);
    }
  }
  // epilogues: mraw -> global + MrB (for u GEMM); hl -> hls
  #pragma unroll
  for (int nt=0;nt<4;nt++){
    int col = c0h*64 + nt*16 + (lane&15);
    float bl = ldr(b_l1, col, bf);
    #pragma unroll
    for (int r=0;r<4;r++){
      int row = qrow + r;
      int w = w0 + row;
      float v = am[nt][r] + cb[((size_t)(b*N_)+w)*M_ + col];
      bf16 mb = f2b(fmaxf(v, 0.f));
      mraw[(((size_t)(b*N_)+i)*N_ + w)*M_ + col] = mb;
      MrB[row][col] = mb;
      hls[row][col] = fmaxf(ah[nt][r] + bl, 0.f);
    }
  }
  __syncthreads();

  // GEMM4: u = MrB @ W_l1 (K=128), bf16 out, no bias
  f32x4 au[4] = {z4,z4,z4,z4};
  for (int kk=0;kk<4;kk++){
    short8 a = *(const short8*)&MrB[mA][kk*32 + kq];
    #pragma unroll
    for (int nt=0;nt<4;nt++){
      short8 b2 = *(const short8*)(pWl1 + (((size_t)kk*8 + c0h*4 + nt)*64 + lane)*8);
      au[nt] = MFMA(a, b2, au[nt]);
    }
  }
  #pragma unroll
  for (int nt=0;nt<4;nt++){
    int col = c0h*64 + nt*16 + (lane&15);
    #pragma unroll
    for (int r=0;r<4;r++)
      ub[(((size_t)(b*N_)+i)*N_ + (size_t)(w0+qrow+r))*M_ + col] = f2b(au[nt][r]);
  }

  // s0 GEMV: 8 lanes per row
  {
    int row = t>>3, seg = t&7;
    float p = 0.f;
    #pragma unroll
    for (int k=0;k<16;k++) p += hls[row][seg*16+k] * ldr(W_l2, seg*16+k, bf);
    p += __shfl_down(p, 4, 8);
    p += __shfl_down(p, 2, 8);
    p += __shfl_down(p, 1, 8);
    if (seg==0 && (w0+row) < valid)
      s0[((size_t)(b*N_)+i)*N_ + w0 + row] = p + ldr(b_l2, 0, bf);
  }
}

// link round, elementwise: s_next[b,i,w] = relu(sig(s_prev[b,w,i])*u[b,w,i,:] + b_l1) . W_l2 + b_l2
__global__ __launch_bounds__(256)
void k_linkE(const bf16* ub, const float* s_prev, const void* b_l1,
             const void* W_l2, const void* b_l2,
             const int* hn, const int* on, float* s_next, const int* dflag)
{
  bool bf = (*dflag != 0);
  int i = blockIdx.x, b = blockIdx.y;
  int valid = hn[b] + on[b];
  if (i >= valid) return;
  int t = threadIdx.x;
  __shared__ float bl1s[M_], wl2s[M_];
  if (t < M_){ bl1s[t] = ldr(b_l1, t, bf); wl2s[t] = ldr(W_l2, t, bf); }
  __syncthreads();
  float bl2 = ldr(b_l2, 0, bf);
  int e = t>>3, seg = t&7;     // 32 edges per pass, 8 lanes/edge, 16 feats/lane
  for (int w0 = 0; w0 < valid; w0 += 32){
    int w = w0 + e;
    if (w >= valid) break;     // uniform within each 8-lane group
    float sg = sigm(s_prev[((size_t)(b*N_)+w)*N_ + i]);
    const short8* up = (const short8*)(ub + (((size_t)(b*N_)+w)*N_ + i)*M_ + seg*16);
    short8 v0 = up[0], v1 = up[1];
    float p = 0.f;
    #pragma unroll
    for (int q=0;q<8;q++){
      int k = seg*16 + q;
      p += fmaxf(sg*s2f(v0[q]) + bl1s[k], 0.f) * wl2s[k];
    }
    #pragma unroll
    for (int q=0;q<8;q++){
      int k = seg*16 + 8 + q;
      p += fmaxf(sg*s2f(v1[q]) + bl1s[k], 0.f) * wl2s[k];
    }
    p += __shfl_down(p, 4, 8);
    p += __shfl_down(p, 2, 8);
    p += __shfl_down(p, 1, 8);
    if (seg==0) s_next[((size_t)(b*N_)+i)*N_ + w] = p + bl2;
  }
}

// fused last link round + final: s2 row -> pred_adj ; m_sum = sum_w sig(s2)*mraw ; GRU ; readout
__global__ __launch_bounds__(256)
void k_linkF(const bf16* ub, const float* s_prev, const bf16* mraw, const float* nf,
             const void* b_l1, const void* W_l2, const void* b_l2,
             const void* W_ih, const void* b_ih, const void* W_hh, const void* b_hh,
             const void* W_ro, const void* b_ro,
             const int* hn, const int* on, void* out, const int* dflag)
{
  bool bf = (*dflag != 0);
  int i = blockIdx.x, b = blockIdx.y;
  int valid = hn[b] + on[b];
  if (i >= valid) return;
  int t = threadIdx.x;  // 256
  __shared__ float bl1s[M_], wl2s[M_];
  __shared__ float sgs[N_];
  __shared__ float pp[2][M_];
  __shared__ float xsh[M_], hsh[M_], hns[M_];
  __shared__ float gout[768];
  if (t < M_){ bl1s[t] = ldr(b_l1, t, bf); wl2s[t] = ldr(W_l2, t, bf); }
  sgs[t] = 0.f;
  __syncthreads();
  float bl2 = ldr(b_l2, 0, bf);
  size_t adj = ((size_t)(b*N_)+i)*N_;
  int e = t>>3, seg = t&7;
  for (int w0 = 0; w0 < valid; w0 += 32){
    int w = w0 + e;
    if (w < valid){
      float sg = sigm(s_prev[((size_t)(b*N_)+w)*N_ + i]);
      const short8* up = (const short8*)(ub + (((size_t)(b*N_)+w)*N_ + i)*M_ + seg*16);
      short8 v0 = up[0], v1 = up[1];
      float p = 0.f;
      #pragma unroll
      for (int q=0;q<8;q++){
        int k = seg*16 + q;
        p += fmaxf(sg*s2f(v0[q]) + bl1s[k], 0.f) * wl2s[k];
      }
      #pragma unroll
      for (int q=0;q<8;q++){
        int k = seg*16 + 8 + q;
        p += fmaxf(sg*s2f(v1[q]) + bl1s[k], 0.f) * wl2s[k];
      }
      p += __shfl_down(p, 4, 8);
      p += __shfl_down(p, 2, 8);
      p += __shfl_down(p, 1, 8);
      if (seg == 0){
        float s2v = p + bl2;
        str(out, adj + w, s2v, bf);
        sgs[w] = sigm(s2v);
      }
    }
  }
  __syncthreads();
  // m_sum over w, split by parity across thread halves
  int f = t & 127, h = t >> 7;
  const short* mrow = (const short*)mraw + adj*M_;
  float acc = 0.f;
  for (int w = h; w < valid; w += 2)
    acc += sgs[w]*s2f(mrow[(size_t)w*M_ + f]);
  pp[h][f] = acc;
  __syncthreads();
  if (h == 0){
    xsh[f] = pp[0][f] + pp[1][f];
    hsh[f] = nf[((size_t)(b*N_)+i)*M_ + f];
  }
  __syncthreads();
  // GRU gates, flattened 768 outputs over 256 threads x 3
  #pragma unroll
  for (int rep=0; rep<3; rep++){
    int j = rep*256 + t;
    int isH = (j >= 384);
    int jj = isH ? (j-384) : j;
    const void* W = isH ? W_hh : W_ih;
    const void* bb = isH ? b_hh : b_ih;
    const float* x = isH ? hsh : xsh;
    float a = ldr(bb, jj, bf);
    for (int k=0;k<128;k++) a += x[k]*ldr(W, (size_t)k*384 + jj, bf);
    gout[j] = a;
  }
  __syncthreads();
  if (t < 128){
    float r  = sigm(gout[t]      + gout[384+t]);
    float z  = sigm(gout[128+t]  + gout[512+t]);
    float nn = tanhf(gout[256+t] + r*gout[640+t]);
    hns[t] = (1.f - z)*nn + z*hsh[t];
  }
  __syncthreads();
  size_t lab = (size_t)ADJ_SZ + ((size_t)(b*N_)+i)*CL_;
  for (int c=t; c<CL_; c+=256){
    float a = ldr(b_ro, c, bf);
    for (int k=0;k<128;k++) a += hns[k]*ldr(W_ro, (size_t)k*CL_ + c, bf);
    str(out, lab + c, a, bf);
  }
}

extern "C" void kernel_launch(void* const* d_in, const int* in_sizes, int n_in,
                              void* d_out, int out_size, void* d_ws, size_t ws_size,
                              hipStream_t stream)
{
  char* ws = (char*)d_ws;

  const void* edgef = d_in[0];
  const void* nodef = d_in[1];
  const int*  hn    = (const int*)d_in[4];
  const int*  on    = (const int*)d_in[5];
  const void* W_er  = d_in[6];  const void* b_er  = d_in[7];
  const void* W_nr  = d_in[8];  const void* b_nr  = d_in[9];
  const void* W_l1  = d_in[10]; const void* b_l1  = d_in[11];
  const void* W_l2  = d_in[12]; const void* b_l2  = d_in[13];
  const void* W_msg = d_in[14]; const void* b_msg = d_in[15];
  const void* W_ih  = d_in[16]; const void* b_ih  = d_in[17];
  const void* W_hh  = d_in[18]; const void* b_hh  = d_in[19];
  const void* W_ro  = d_in[20]; const void* b_ro  = d_in[21];

  bf16*  mraw   = (bf16*) (ws);                 // [0, 64 MiB)
  bf16*  ub     = (bf16*) (ws + 67108864);      // [64, 128 MiB)  -- 64 MiB!
  float* s_a    = (float*)(ws + 134217728);     // 1 MiB
  float* s_b    = (float*)(ws + 135266304);     // 1 MiB
  float* nf     = (float*)(ws + 136314880);     // 512 KiB
  float* cb     = (float*)(ws + 136839168);     // 512 KiB
  bf16*  pWer   = (bf16*) (ws + 137363456);     // 64 KiB
  bf16*  pWmsgB = (bf16*) (ws + 137428992);     // 32 KiB
  bf16*  pWl1   = (bf16*) (ws + 137461760);     // 32 KiB
  int*   dflag  = (int*)  (ws + 137494528);

  k_detect<<<1, 64, 0, stream>>>((const unsigned short*)d_in[0], dflag);

  int nzb = (out_size + 255) / 256;
  k_prep<<<nzb + 32 + 1024, 256, 0, stream>>>(
      W_er, W_msg, W_l1, nodef, W_nr, b_nr, b_msg,
      pWer, pWmsgB, pWl1, nf, cb, d_out, out_size, dflag);

  dim3 g2(N_/32, N_, B_);
  k_r0<<<g2, 256, 0, stream>>>(edgef, pWer, b_er, pWmsgB, cb, pWl1,
                               b_l1, W_l2, b_l2, hn, on, mraw, ub, s_a, dflag);

  dim3 gl(N_, B_);
  k_linkE<<<gl, 256, 0, stream>>>(ub, s_a, b_l1, W_l2, b_l2, hn, on, s_b, dflag);
  k_linkF<<<gl, 256, 0, stream>>>(ub, s_b, mraw, nf, b_l1, W_l2, b_l2,
                                  W_ih, b_ih, W_hh, b_hh, W_ro, b_ro,
                                  hn, on, d_out, dflag);
}

// Round 4
// 539.317 us; speedup vs baseline: 1.1492x; 1.1492x over previous
//
#include <hip/hip_runtime.h>
#include <hip/hip_bf16.h>

// GPNN_HICO: B=4, N=256, EDGE_F=256, MSG=128, LINK_H=128, ROUNDS=3, CLASSES=600
// Algebra:
//  - only the valid[b] x valid[b] block matters
//  - m_raw is round-invariant
//  - link rounds: relu(sig(s)*(mraw @ W_l1) + b_l1) . W_l2  (scalar gate commutes
//    with the GEMM) => recompute the tiny GEMM per round from mraw via MFMA
//    instead of materializing u (saves ~236 MB of traffic vs fp32-u pipeline).
// Structure = R1 (best measured 512.7us): detect, prep, nf_c, r0, linkM x2, final.

#define B_ 4
#define N_ 256
#define EF_ 256
#define M_ 128
#define CL_ 600
#define ADJ_SZ (B_*N_*N_)

typedef __hip_bfloat16 bf16;
typedef short short8 __attribute__((ext_vector_type(8)));
typedef float f32x4 __attribute__((ext_vector_type(4)));
typedef float fvec4 __attribute__((ext_vector_type(4)));

#define MFMA(a,b,c) __builtin_amdgcn_mfma_f32_16x16x32_bf16(a,b,c,0,0,0)

__device__ __forceinline__ float s2f(short s){
  union { unsigned int u; float f; } x; x.u = ((unsigned int)(unsigned short)s) << 16; return x.f;
}
__device__ __forceinline__ bf16 f2b(float f){ return __float2bfloat16(f); }
__device__ __forceinline__ float sigm(float x){ return 1.0f/(1.0f+expf(-x)); }

__device__ __forceinline__ float ldr(const void* p, size_t i, bool bf){
  return bf ? s2f(((const short*)p)[i]) : ((const float*)p)[i];
}
__device__ __forceinline__ void str(void* p, size_t i, float v, bool bf){
  if (bf) ((bf16*)p)[i] = f2b(v);
  else    ((float*)p)[i] = v;
}
__device__ __forceinline__ float dot8(short8 w, const float* x){
  float a = 0.f;
  #pragma unroll
  for (int j=0;j<8;j++) a += x[j]*s2f(w[j]);
  return a;
}

// ---- dtype detector: bf16 buffers ~100% sane exponents; fp32-as-u16 ~59% ----
__global__ __launch_bounds__(64)
void k_detect(const unsigned short* ef, int* flag){
  int t = threadIdx.x;
  int cnt = 0;
  for (int j = 0; j < 64; j++){
    unsigned short u = ef[t*64 + j];
    int e = (u >> 7) & 0xFF;
    cnt += (e >= 96 && e <= 144) ? 1 : 0;
  }
  for (int o = 32; o > 0; o >>= 1) cnt += __shfl_down(cnt, o, 64);
  if (t == 0) *flag = (cnt > 3500) ? 1 : 0;
}

// ---- merged prep: zero output | MFMA-pack 3 weights | transpose 5 weights ----
// block ranges: [0,nzb) zero ; [nzb,nzb+32) packs (4 units/block) ;
//               [nzb+32, nzb+32+876) transposes (224256 elems total)
__global__ __launch_bounds__(256)
void k_prep(const void* W_er, const void* W_msg, const void* W_l1,
            const void* W_nr, const void* W_ih, const void* W_hh, const void* W_ro,
            bf16* pWer, bf16* pWmsgB, bf16* pWl1,
            bf16* tWnr, bf16* tWmsgT, bf16* tWih, bf16* tWhh, bf16* tWro,
            void* out, int out_size, const int* dflag)
{
  bool bf = (*dflag != 0);
  int nzb = (out_size + 255) >> 8;
  int blk = blockIdx.x;
  int t = threadIdx.x;
  if (blk < nzb){
    int i = blk*256 + t;
    if (i < out_size) str(out, i, 0.f, bf);
    return;
  }
  blk -= nzb;
  if (blk < 32){
    // MFMA B-fragment pack: dst[(u2*64+lane)*8+j] = src[(kk*32+(lane>>4)*8+j)*128 + nt*16+(lane&15)]
    int unit = blk*4 + (t>>6);
    int lane = t & 63;
    const void* src; bf16* dst; int u2;
    if (unit < 64){ src = W_er; dst = pWer; u2 = unit; }            // K=256,N=128
    else if (unit < 96){                                            // K=128,N=128
      src = bf ? (const void*)((const short*)W_msg + 128*M_)
               : (const void*)((const float*)W_msg + 128*M_);
      dst = pWmsgB; u2 = unit - 64;
    } else { src = W_l1; dst = pWl1; u2 = unit - 96; }              // K=128,N=128
    int kk = u2 >> 3, nt = u2 & 7;
    int k0 = kk*32 + (lane>>4)*8;
    int n  = nt*16 + (lane&15);
    size_t dbase = ((size_t)u2*64 + lane)*8;
    #pragma unroll
    for (int j=0;j<8;j++)
      dst[dbase+j] = f2b(ldr(src, (size_t)(k0+j)*128 + n, bf));
    return;
  }
  blk -= 32;
  int idx = blk*256 + t;
  const void* src; bf16* dst; int K, N;
  if (idx < 32768){ src = W_nr;  dst = tWnr;  K = 256; N = 128; }
  else if ((idx -= 32768) < 16384){ src = W_msg; dst = tWmsgT; K = 128; N = 128; }
  else if ((idx -= 16384) < 49152){ src = W_ih;  dst = tWih;  K = 128; N = 384; }
  else if ((idx -= 49152) < 49152){ src = W_hh;  dst = tWhh;  K = 128; N = 384; }
  else if ((idx -= 49152) < 76800){ src = W_ro;  dst = tWro;  K = 128; N = 600; }
  else return;
  int k = idx / N, n = idx % N;
  dst[(size_t)n*K + k] = f2b(ldr(src, idx, bf));
}

// nf[b,v,:] = node @ W_nr + b_nr ; cb[b,v,:] = b_msg + nf @ W_msg[0:128,:]
__global__ __launch_bounds__(128)
void k_nf_c(const void* nodef, const bf16* tWnr, const void* b_nr,
            const bf16* tWmsgT, const void* b_msg, float* nf, float* cb,
            const int* dflag)
{
  bool bf = (*dflag != 0);
  int blk = blockIdx.x; int b = blk >> 8; int v = blk & 255;
  int t = threadIdx.x;  // 128
  __shared__ float xs[EF_];
  __shared__ float nfs[M_];
  size_t xrow = ((size_t)(b*N_)+v)*EF_;
  xs[t]     = ldr(nodef, xrow + t, bf);
  xs[t+128] = ldr(nodef, xrow + t + 128, bf);
  __syncthreads();
  float acc = ldr(b_nr, t, bf);
  const short8* wp = (const short8*)(tWnr + (size_t)t*EF_);
  #pragma unroll 4
  for (int k8=0;k8<32;k8++) acc += dot8(wp[k8], &xs[k8*8]);
  nf[((size_t)(b*N_)+v)*M_+t] = acc;
  nfs[t] = acc;
  __syncthreads();
  float acc2 = ldr(b_msg, t, bf);
  const short8* wq = (const short8*)(tWmsgT + (size_t)t*M_);
  #pragma unroll 4
  for (int k8=0;k8<16;k8++) acc2 += dot8(wq[k8], &nfs[k8*8]);
  cb[((size_t)(b*N_)+v)*M_+t] = acc2;
}

// Fused round 0 per (b, i, 32-w tile): MFMA GEMMs.
//   ef   = edge @ W_er + b_er
//   mraw = relu(cb[b,w] + ef @ W_msg[128:,:])   (bf16 to global)
//   s0   = relu(ef @ W_l1 + b_l1) @ W_l2 + b_l2
__global__ __launch_bounds__(256)
void k_r0(const void* edgef, const bf16* pWer, const void* b_er,
          const bf16* pWmsgB, const float* cb, const bf16* pWl1,
          const void* b_l1, const void* W_l2, const void* b_l2,
          const int* hn, const int* on, bf16* mraw, float* s0,
          const int* dflag)
{
  bool bf = (*dflag != 0);
  int b = blockIdx.z, i = blockIdx.y, w0 = blockIdx.x*32;
  int valid = hn[b] + on[b];
  if (i >= valid || w0 >= valid) return;
  int t = threadIdx.x;
  __shared__ __attribute__((aligned(16))) bf16 EfsB[32][136];
  __shared__ __attribute__((aligned(16))) char uni[32*264*2]; // Xs bf16[32][264] | hls f32[32][132]
  bf16  (*Xs)[264]  = (bf16(*)[264])uni;
  float (*hls)[132] = (float(*)[132])uni;

  // stage edge rows [32][256]
  {
    int j = t>>3, c = (t&7)*32;
    size_t g = (((size_t)(b*N_)+i)*N_ + (size_t)(w0+j))*EF_ + c;
    if (bf){
      const short8* src = (const short8*)((const short*)edgef + g);
      short8* dst = (short8*)&Xs[j][c];
      #pragma unroll
      for (int q=0;q<4;q++) dst[q] = src[q];
    } else {
      const fvec4* src = (const fvec4*)((const float*)edgef + g);
      #pragma unroll
      for (int q=0;q<8;q++){
        fvec4 v = src[q];
        #pragma unroll
        for (int e=0;e<4;e++) Xs[j][c+q*4+e] = f2b(v[e]);
      }
    }
  }
  __syncthreads();

  int lane = t & 63, wv = t >> 6;
  int r0 = (wv&1)*16;
  int c0h = wv >> 1;               // column half (0/1), 64 cols each
  int mA = r0 + (lane&15);
  int kq = (lane>>4)*8;
  int qrow = r0 + (lane>>4)*4;

  f32x4 z4 = {0.f,0.f,0.f,0.f};
  f32x4 acc[4] = {z4,z4,z4,z4};
  for (int kk=0;kk<8;kk++){
    short8 a = *(const short8*)&Xs[mA][kk*32 + kq];
    #pragma unroll
    for (int nt=0;nt<4;nt++){
      int gnt = c0h*4 + nt;
      short8 bb = *(const short8*)(pWer + (((size_t)kk*8 + gnt)*64 + lane)*8);
      acc[nt] = MFMA(a, bb, acc[nt]);
    }
  }
  // ef -> LDS bf16 (with bias)
  #pragma unroll
  for (int nt=0;nt<4;nt++){
    int col = c0h*64 + nt*16 + (lane&15);
    float be = ldr(b_er, col, bf);
    #pragma unroll
    for (int r=0;r<4;r++)
      EfsB[qrow+r][col] = f2b(acc[nt][r] + be);
  }
  __syncthreads();

  // GEMM2 (mraw) + GEMM3 (hl), shared A-frags, K=128
  f32x4 am[4] = {z4,z4,z4,z4};
  f32x4 ah[4] = {z4,z4,z4,z4};
  for (int kk=0;kk<4;kk++){
    short8 a = *(const short8*)&EfsB[mA][kk*32 + kq];
    #pragma unroll
    for (int nt=0;nt<4;nt++){
      int gnt = c0h*4 + nt;
      size_t off = (((size_t)kk*8 + gnt)*64 + lane)*8;
      short8 b1 = *(const short8*)(pWmsgB + off);
      am[nt] = MFMA(a, b1, am[nt]);
      short8 b2 = *(const short8*)(pWl1 + off);
      ah[nt] = MFMA(a, b2, ah[nt]);
    }
  }
  // epilogues: mraw -> global; hl -> hls
  #pragma unroll
  for (int nt=0;nt<4;nt++){
    int col = c0h*64 + nt*16 + (lane&15);
    float bl = ldr(b_l1, col, bf);
    #pragma unroll
    for (int r=0;r<4;r++){
      int row = qrow + r;
      int w = w0 + row;
      float v = am[nt][r] + cb[((size_t)(b*N_)+w)*M_ + col];
      mraw[(((size_t)(b*N_)+i)*N_ + w)*M_ + col] = f2b(fmaxf(v, 0.f));
      hls[row][col] = fmaxf(ah[nt][r] + bl, 0.f);
    }
  }
  __syncthreads();
  // s0 GEMV: 8 lanes per row
  {
    int row = t>>3, seg = t&7;
    float p = 0.f;
    #pragma unroll
    for (int k=0;k<16;k++) p += hls[row][seg*16+k] * ldr(W_l2, seg*16+k, bf);
    p += __shfl_down(p, 4, 8);
    p += __shfl_down(p, 2, 8);
    p += __shfl_down(p, 1, 8);
    if (seg==0 && (w0+row) < valid)
      s0[((size_t)(b*N_)+i)*N_ + w0 + row] = p + ldr(b_l2, 0, bf);
  }
}

// link round via MFMA from mraw (no materialized u):
// s_next[b,i,w] = relu(sig(s_prev[b,w,i]) * (mraw[b,w,i,:] @ W_l1) + b_l1) . W_l2 + b_l2
__global__ __launch_bounds__(256)
void k_linkM(const bf16* mraw, const float* s_prev, const bf16* pWl1,
             const void* b_l1, const void* W_l2, const void* b_l2,
             const int* hn, const int* on, float* s_next, const int* dflag)
{
  bool bf = (*dflag != 0);
  int b = blockIdx.z, i = blockIdx.y, w0 = blockIdx.x*32;
  int valid = hn[b] + on[b];
  if (i >= valid || w0 >= valid) return;
  int t = threadIdx.x;
  __shared__ __attribute__((aligned(16))) bf16 Ms[32][136];
  __shared__ __attribute__((aligned(16))) float hls[32][132];
  __shared__ float sg[32];
  if (t < 32){
    int w = w0 + t;
    sg[t] = (w < valid) ? sigm(s_prev[((size_t)(b*N_)+w)*N_ + i]) : 0.f;
  }
  // stage mraw rows [32][128] (row j = mraw[b, w0+j, i, :])
  {
    int j = t>>3, c = (t&7)*16;
    const short8* src = (const short8*)((const short*)mraw +
        (((size_t)(b*N_)+(size_t)(w0+j))*N_ + i)*M_ + c);
    short8* dst = (short8*)&Ms[j][c];
    dst[0] = src[0]; dst[1] = src[1];
  }
  __syncthreads();

  int lane = t & 63, wv = t >> 6;
  int r0 = (wv&1)*16;
  int c0h = wv >> 1;
  int mA = r0 + (lane&15);
  int kq = (lane>>4)*8;
  int qrow = r0 + (lane>>4)*4;

  f32x4 z4 = {0.f,0.f,0.f,0.f};
  f32x4 ah[4] = {z4,z4,z4,z4};
  for (int kk=0;kk<4;kk++){
    short8 a = *(const short8*)&Ms[mA][kk*32 + kq];
    #pragma unroll
    for (int nt=0;nt<4;nt++){
      short8 b2 = *(const short8*)(pWl1 + (((size_t)kk*8 + c0h*4 + nt)*64 + lane)*8);
      ah[nt] = MFMA(a, b2, ah[nt]);
    }
  }
  // gate AFTER the GEMM (scalar per row), then bias+relu
  #pragma unroll
  for (int nt=0;nt<4;nt++){
    int col = c0h*64 + nt*16 + (lane&15);
    float bl = ldr(b_l1, col, bf);
    #pragma unroll
    for (int r=0;r<4;r++){
      int row = qrow + r;
      hls[row][col] = fmaxf(sg[row]*ah[nt][r] + bl, 0.f);
    }
  }
  __syncthreads();
  {
    int row = t>>3, seg = t&7;
    float p = 0.f;
    #pragma unroll
    for (int k=0;k<16;k++) p += hls[row][seg*16+k] * ldr(W_l2, seg*16+k, bf);
    p += __shfl_down(p, 4, 8);
    p += __shfl_down(p, 2, 8);
    p += __shfl_down(p, 1, 8);
    if (seg==0 && (w0+row) < valid)
      s_next[((size_t)(b*N_)+i)*N_ + w0 + row] = p + ldr(b_l2, 0, bf);
  }
}

// final: pred_adj = s2 ; m_sum = sum_w sig(s2)*mraw ; GRU ; readout
__global__ __launch_bounds__(128)
void k_final(const bf16* mraw, const float* s2, const float* nf,
             const bf16* tWih, const void* b_ih,
             const bf16* tWhh, const void* b_hh,
             const bf16* tWro, const void* b_ro,
             const int* hn, const int* on, void* out, const int* dflag)
{
  bool bf = (*dflag != 0);
  int i = blockIdx.x, b = blockIdx.y;
  int valid = hn[b] + on[b];
  if (i >= valid) return;
  int t = threadIdx.x;  // 128
  __shared__ float sgs[N_];
  __shared__ float xsh[M_], hsh[M_], hns[M_];
  const float* srow = s2 + ((size_t)(b*N_)+i)*N_;
  size_t adj = ((size_t)(b*N_)+i)*N_;
  for (int w=t; w<N_; w+=128){
    if (w < valid){
      float v = srow[w];
      str(out, adj + w, v, bf);
      sgs[w] = sigm(v);
    } else sgs[w] = 0.f;
  }
  __syncthreads();
  const short* mrow = (const short*)mraw + (((size_t)(b*N_)+i)*N_)*M_;
  float acc = 0.f;
  for (int w=0; w<valid; w++) acc += sgs[w]*s2f(mrow[(size_t)w*M_ + t]);
  xsh[t] = acc;
  hsh[t] = nf[((size_t)(b*N_)+i)*M_ + t];
  __syncthreads();
  float gi[3], gh[3];
  #pragma unroll
  for (int g=0; g<3; g++){
    int o = g*M_ + t;
    float a = ldr(b_ih, o, bf), c = ldr(b_hh, o, bf);
    const short8* wi = (const short8*)(tWih + (size_t)o*M_);
    const short8* wh = (const short8*)(tWhh + (size_t)o*M_);
    #pragma unroll 4
    for (int k8=0;k8<16;k8++){
      a += dot8(wi[k8], &xsh[k8*8]);
      c += dot8(wh[k8], &hsh[k8*8]);
    }
    gi[g] = a; gh[g] = c;
  }
  float r  = sigm(gi[0] + gh[0]);
  float z  = sigm(gi[1] + gh[1]);
  float nn = tanhf(gi[2] + r*gh[2]);
  float hnew = (1.f - z)*nn + z*hsh[t];
  hns[t] = hnew;
  __syncthreads();
  size_t lab = (size_t)ADJ_SZ + ((size_t)(b*N_)+i)*CL_;
  for (int cls=t; cls<CL_; cls+=128){
    float a = ldr(b_ro, cls, bf);
    const short8* wr = (const short8*)(tWro + (size_t)cls*M_);
    #pragma unroll 4
    for (int k8=0;k8<16;k8++) a += dot8(wr[k8], &hns[k8*8]);
    str(out, lab + cls, a, bf);
  }
}

extern "C" void kernel_launch(void* const* d_in, const int* in_sizes, int n_in,
                              void* d_out, int out_size, void* d_ws, size_t ws_size,
                              hipStream_t stream)
{
  char* ws = (char*)d_ws;

  const void* edgef = d_in[0];
  const void* nodef = d_in[1];
  const int*  hn    = (const int*)d_in[4];
  const int*  on    = (const int*)d_in[5];
  const void* W_er  = d_in[6];  const void* b_er  = d_in[7];
  const void* W_nr  = d_in[8];  const void* b_nr  = d_in[9];
  const void* W_l1  = d_in[10]; const void* b_l1  = d_in[11];
  const void* W_l2  = d_in[12]; const void* b_l2  = d_in[13];
  const void* W_msg = d_in[14]; const void* b_msg = d_in[15];
  const void* W_ih  = d_in[16]; const void* b_ih  = d_in[17];
  const void* W_hh  = d_in[18]; const void* b_hh  = d_in[19];
  const void* W_ro  = d_in[20]; const void* b_ro  = d_in[21];

  bf16*  mraw   = (bf16*) (ws);                 // [0, 64 MiB)
  float* s_a    = (float*)(ws + 67108864);      // 1 MiB
  float* s_b    = (float*)(ws + 68157440);      // 1 MiB
  float* nf     = (float*)(ws + 69206016);      // 512 KiB
  float* cb     = (float*)(ws + 69730304);      // 512 KiB
  bf16*  pWer   = (bf16*) (ws + 70254592);      // 64 KiB
  bf16*  pWmsgB = (bf16*) (ws + 70320128);      // 32 KiB
  bf16*  pWl1   = (bf16*) (ws + 70352896);      // 32 KiB
  bf16*  tWnr   = (bf16*) (ws + 70385664);      // 64 KiB
  bf16*  tWmsgT = (bf16*) (ws + 70451200);      // 32 KiB
  bf16*  tWih   = (bf16*) (ws + 70483968);      // 96 KiB
  bf16*  tWhh   = (bf16*) (ws + 70582272);      // 96 KiB
  bf16*  tWro   = (bf16*) (ws + 70680576);      // 150 KiB
  int*   dflag  = (int*)  (ws + 70834176);

  k_detect<<<1, 64, 0, stream>>>((const unsigned short*)d_in[0], dflag);

  int nzb = (out_size + 255) / 256;
  k_prep<<<nzb + 32 + 876, 256, 0, stream>>>(
      W_er, W_msg, W_l1, W_nr, W_ih, W_hh, W_ro,
      pWer, pWmsgB, pWl1, tWnr, tWmsgT, tWih, tWhh, tWro,
      d_out, out_size, dflag);

  k_nf_c<<<B_*N_, 128, 0, stream>>>(nodef, tWnr, b_nr, tWmsgT, b_msg, nf, cb, dflag);

  dim3 g2(N_/32, N_, B_);
  k_r0<<<g2, 256, 0, stream>>>(edgef, pWer, b_er, pWmsgB, cb, pWl1,
                               b_l1, W_l2, b_l2, hn, on, mraw, s_a, dflag);

  k_linkM<<<g2, 256, 0, stream>>>(mraw, s_a, pWl1, b_l1, W_l2, b_l2, hn, on, s_b, dflag);
  k_linkM<<<g2, 256, 0, stream>>>(mraw, s_b, pWl1, b_l1, W_l2, b_l2, hn, on, s_a, dflag);

  dim3 gl(N_, B_);
  k_final<<<gl, 128, 0, stream>>>(mraw, s_a, nf, tWih, b_ih, tWhh, b_hh,
                                  tWro, b_ro, hn, on, d_out, dflag);
}

// Round 5
// 502.605 us; speedup vs baseline: 1.2331x; 1.0730x over previous
//
#include <hip/hip_runtime.h>
#include <hip/hip_bf16.h>

// GPNN_HICO: B=4, N=256, EDGE_F=256, MSG=128, LINK_H=128, ROUNDS=3, CLASSES=600
// Algebra:
//  - only the valid[b] x valid[b] block matters
//  - m_raw is round-invariant
//  - link rounds: e_state @ W_l1 = sig(s)*(mraw @ W_l1) = sig(s)*u  (scalar gate)
//    => precompute u ONCE in k_r0 (GEMM4, shares the staged mraw tile);
//       link rounds are pure elementwise streams over u.
// R5 = R1 (best measured, 512.7us) + two minimal diffs:
//   (a) u stored bf16 (halves u write + both link-round reads; accuracy
//       validated in R3: absmax 0.0078)
//   (b) linkE grid 1024 -> 8192 blocks (one 32-w slab per block, no w-loop)

#define B_ 4
#define N_ 256
#define EF_ 256
#define M_ 128
#define CL_ 600
#define ADJ_SZ (B_*N_*N_)

typedef __hip_bfloat16 bf16;
typedef short short8 __attribute__((ext_vector_type(8)));
typedef float f32x4 __attribute__((ext_vector_type(4)));
typedef float fvec4 __attribute__((ext_vector_type(4)));

#define MFMA(a,b,c) __builtin_amdgcn_mfma_f32_16x16x32_bf16(a,b,c,0,0,0)

__device__ __forceinline__ float s2f(short s){
  union { unsigned int u; float f; } x; x.u = ((unsigned int)(unsigned short)s) << 16; return x.f;
}
__device__ __forceinline__ bf16 f2b(float f){ return __float2bfloat16(f); }
__device__ __forceinline__ float sigm(float x){ return 1.0f/(1.0f+expf(-x)); }

__device__ __forceinline__ float ldr(const void* p, size_t i, bool bf){
  return bf ? s2f(((const short*)p)[i]) : ((const float*)p)[i];
}
__device__ __forceinline__ void str(void* p, size_t i, float v, bool bf){
  if (bf) ((bf16*)p)[i] = f2b(v);
  else    ((float*)p)[i] = v;
}
__device__ __forceinline__ float dot8(short8 w, const float* x){
  float a = 0.f;
  #pragma unroll
  for (int j=0;j<8;j++) a += x[j]*s2f(w[j]);
  return a;
}

// ---- dtype detector: bf16 buffers ~100% sane exponents; fp32-as-u16 ~59% ----
__global__ __launch_bounds__(64)
void k_detect(const unsigned short* ef, int* flag){
  int t = threadIdx.x;
  int cnt = 0;
  for (int j = 0; j < 64; j++){
    unsigned short u = ef[t*64 + j];
    int e = (u >> 7) & 0xFF;
    cnt += (e >= 96 && e <= 144) ? 1 : 0;
  }
  for (int o = 32; o > 0; o >>= 1) cnt += __shfl_down(cnt, o, 64);
  if (t == 0) *flag = (cnt > 3500) ? 1 : 0;
}

// ---- merged prep: zero output | MFMA-pack 3 weights | transpose 5 weights ----
// block ranges: [0,nzb) zero ; [nzb,nzb+32) packs (4 units/block) ;
//               [nzb+32, nzb+32+876) transposes (224256 elems total)
__global__ __launch_bounds__(256)
void k_prep(const void* W_er, const void* W_msg, const void* W_l1,
            const void* W_nr, const void* W_ih, const void* W_hh, const void* W_ro,
            bf16* pWer, bf16* pWmsgB, bf16* pWl1,
            bf16* tWnr, bf16* tWmsgT, bf16* tWih, bf16* tWhh, bf16* tWro,
            void* out, int out_size, const int* dflag)
{
  bool bf = (*dflag != 0);
  int nzb = (out_size + 255) >> 8;
  int blk = blockIdx.x;
  int t = threadIdx.x;
  if (blk < nzb){
    int i = blk*256 + t;
    if (i < out_size) str(out, i, 0.f, bf);
    return;
  }
  blk -= nzb;
  if (blk < 32){
    // MFMA B-fragment pack: dst[(u2*64+lane)*8+j] = src[(kk*32+(lane>>4)*8+j)*128 + nt*16+(lane&15)]
    int unit = blk*4 + (t>>6);
    int lane = t & 63;
    const void* src; bf16* dst; int u2;
    if (unit < 64){ src = W_er; dst = pWer; u2 = unit; }            // K=256,N=128
    else if (unit < 96){                                            // K=128,N=128
      src = bf ? (const void*)((const short*)W_msg + 128*M_)
               : (const void*)((const float*)W_msg + 128*M_);
      dst = pWmsgB; u2 = unit - 64;
    } else { src = W_l1; dst = pWl1; u2 = unit - 96; }              // K=128,N=128
    int kk = u2 >> 3, nt = u2 & 7;
    int k0 = kk*32 + (lane>>4)*8;
    int n  = nt*16 + (lane&15);
    size_t dbase = ((size_t)u2*64 + lane)*8;
    #pragma unroll
    for (int j=0;j<8;j++)
      dst[dbase+j] = f2b(ldr(src, (size_t)(k0+j)*128 + n, bf));
    return;
  }
  blk -= 32;
  int idx = blk*256 + t;
  const void* src; bf16* dst; int K, N;
  if (idx < 32768){ src = W_nr;  dst = tWnr;  K = 256; N = 128; }
  else if ((idx -= 32768) < 16384){ src = W_msg; dst = tWmsgT; K = 128; N = 128; }
  else if ((idx -= 16384) < 49152){ src = W_ih;  dst = tWih;  K = 128; N = 384; }
  else if ((idx -= 49152) < 49152){ src = W_hh;  dst = tWhh;  K = 128; N = 384; }
  else if ((idx -= 49152) < 76800){ src = W_ro;  dst = tWro;  K = 128; N = 600; }
  else return;
  int k = idx / N, n = idx % N;
  dst[(size_t)n*K + k] = f2b(ldr(src, idx, bf));
}

// nf[b,v,:] = node @ W_nr + b_nr ; cb[b,v,:] = b_msg + nf @ W_msg[0:128,:]
__global__ __launch_bounds__(128)
void k_nf_c(const void* nodef, const bf16* tWnr, const void* b_nr,
            const bf16* tWmsgT, const void* b_msg, float* nf, float* cb,
            const int* dflag)
{
  bool bf = (*dflag != 0);
  int blk = blockIdx.x; int b = blk >> 8; int v = blk & 255;
  int t = threadIdx.x;  // 128
  __shared__ float xs[EF_];
  __shared__ float nfs[M_];
  size_t xrow = ((size_t)(b*N_)+v)*EF_;
  xs[t]     = ldr(nodef, xrow + t, bf);
  xs[t+128] = ldr(nodef, xrow + t + 128, bf);
  __syncthreads();
  float acc = ldr(b_nr, t, bf);
  const short8* wp = (const short8*)(tWnr + (size_t)t*EF_);
  #pragma unroll 4
  for (int k8=0;k8<32;k8++) acc += dot8(wp[k8], &xs[k8*8]);
  nf[((size_t)(b*N_)+v)*M_+t] = acc;
  nfs[t] = acc;
  __syncthreads();
  float acc2 = ldr(b_msg, t, bf);
  const short8* wq = (const short8*)(tWmsgT + (size_t)t*M_);
  #pragma unroll 4
  for (int k8=0;k8<16;k8++) acc2 += dot8(wq[k8], &nfs[k8*8]);
  cb[((size_t)(b*N_)+v)*M_+t] = acc2;
}

// Fused round 0 per (b, i, 32-w tile): MFMA GEMMs.
//   ef   = edge @ W_er + b_er
//   mraw = relu(cb[b,w] + ef @ W_msg[128:,:])   (bf16 to global + LDS)
//   s0   = relu(ef @ W_l1 + b_l1) @ W_l2 + b_l2
//   u    = mraw @ W_l1                           (bf16 to global)
__global__ __launch_bounds__(256)
void k_r0(const void* edgef, const bf16* pWer, const void* b_er,
          const bf16* pWmsgB, const float* cb, const bf16* pWl1,
          const void* b_l1, const void* W_l2, const void* b_l2,
          const int* hn, const int* on, bf16* mraw, bf16* ub, float* s0,
          const int* dflag)
{
  bool bf = (*dflag != 0);
  int b = blockIdx.z, i = blockIdx.y, w0 = blockIdx.x*32;
  int valid = hn[b] + on[b];
  if (i >= valid || w0 >= valid) return;
  int t = threadIdx.x;
  __shared__ __attribute__((aligned(16))) bf16 EfsB[32][136];
  __shared__ __attribute__((aligned(16))) bf16 MrB[32][136];
  __shared__ __attribute__((aligned(16))) char uni[32*264*2]; // Xs bf16[32][264] | hls f32[32][132]
  bf16  (*Xs)[264]  = (bf16(*)[264])uni;
  float (*hls)[132] = (float(*)[132])uni;

  // stage edge rows [32][256]
  {
    int j = t>>3, c = (t&7)*32;
    size_t g = (((size_t)(b*N_)+i)*N_ + (size_t)(w0+j))*EF_ + c;
    if (bf){
      const short8* src = (const short8*)((const short*)edgef + g);
      short8* dst = (short8*)&Xs[j][c];
      #pragma unroll
      for (int q=0;q<4;q++) dst[q] = src[q];
    } else {
      const fvec4* src = (const fvec4*)((const float*)edgef + g);
      #pragma unroll
      for (int q=0;q<8;q++){
        fvec4 v = src[q];
        #pragma unroll
        for (int e=0;e<4;e++) Xs[j][c+q*4+e] = f2b(v[e]);
      }
    }
  }
  __syncthreads();

  int lane = t & 63, wv = t >> 6;
  int r0 = (wv&1)*16;
  int c0h = wv >> 1;               // column half (0/1), 64 cols each
  int mA = r0 + (lane&15);
  int kq = (lane>>4)*8;
  int qrow = r0 + (lane>>4)*4;

  f32x4 z4 = {0.f,0.f,0.f,0.f};
  f32x4 acc[4] = {z4,z4,z4,z4};
  for (int kk=0;kk<8;kk++){
    short8 a = *(const short8*)&Xs[mA][kk*32 + kq];
    #pragma unroll
    for (int nt=0;nt<4;nt++){
      int gnt = c0h*4 + nt;
      short8 bb = *(const short8*)(pWer + (((size_t)kk*8 + gnt)*64 + lane)*8);
      acc[nt] = MFMA(a, bb, acc[nt]);
    }
  }
  // ef -> LDS bf16 (with bias)
  #pragma unroll
  for (int nt=0;nt<4;nt++){
    int col = c0h*64 + nt*16 + (lane&15);
    float be = ldr(b_er, col, bf);
    #pragma unroll
    for (int r=0;r<4;r++)
      EfsB[qrow+r][col] = f2b(acc[nt][r] + be);
  }
  __syncthreads();

  // GEMM2 (mraw) + GEMM3 (hl), shared A-frags, K=128
  f32x4 am[4] = {z4,z4,z4,z4};
  f32x4 ah[4] = {z4,z4,z4,z4};
  for (int kk=0;kk<4;kk++){
    short8 a = *(const short8*)&EfsB[mA][kk*32 + kq];
    #pragma unroll
    for (int nt=0;nt<4;nt++){
      int gnt = c0h*4 + nt;
      size_t off = (((size_t)kk*8 + gnt)*64 + lane)*8;
      short8 b1 = *(const short8*)(pWmsgB + off);
      am[nt] = MFMA(a, b1, am[nt]);
      short8 b2 = *(const short8*)(pWl1 + off);
      ah[nt] = MFMA(a, b2, ah[nt]);
    }
  }
  // epilogues: mraw -> global + MrB (for u GEMM); hl -> hls
  #pragma unroll
  for (int nt=0;nt<4;nt++){
    int col = c0h*64 + nt*16 + (lane&15);
    float bl = ldr(b_l1, col, bf);
    #pragma unroll
    for (int r=0;r<4;r++){
      int row = qrow + r;
      int w = w0 + row;
      float v = am[nt][r] + cb[((size_t)(b*N_)+w)*M_ + col];
      bf16 mb = f2b(fmaxf(v, 0.f));
      mraw[(((size_t)(b*N_)+i)*N_ + w)*M_ + col] = mb;
      MrB[row][col] = mb;
      hls[row][col] = fmaxf(ah[nt][r] + bl, 0.f);
    }
  }
  __syncthreads();

  // GEMM4: u = MrB @ W_l1 (K=128), bf16 out, no bias
  f32x4 au[4] = {z4,z4,z4,z4};
  for (int kk=0;kk<4;kk++){
    short8 a = *(const short8*)&MrB[mA][kk*32 + kq];
    #pragma unroll
    for (int nt=0;nt<4;nt++){
      short8 b2 = *(const short8*)(pWl1 + (((size_t)kk*8 + c0h*4 + nt)*64 + lane)*8);
      au[nt] = MFMA(a, b2, au[nt]);
    }
  }
  #pragma unroll
  for (int nt=0;nt<4;nt++){
    int col = c0h*64 + nt*16 + (lane&15);
    #pragma unroll
    for (int r=0;r<4;r++)
      ub[(((size_t)(b*N_)+i)*N_ + (size_t)(w0+qrow+r))*M_ + col] = f2b(au[nt][r]);
  }

  // s0 GEMV: 8 lanes per row
  {
    int row = t>>3, seg = t&7;
    float p = 0.f;
    #pragma unroll
    for (int k=0;k<16;k++) p += hls[row][seg*16+k] * ldr(W_l2, seg*16+k, bf);
    p += __shfl_down(p, 4, 8);
    p += __shfl_down(p, 2, 8);
    p += __shfl_down(p, 1, 8);
    if (seg==0 && (w0+row) < valid)
      s0[((size_t)(b*N_)+i)*N_ + w0 + row] = p + ldr(b_l2, 0, bf);
  }
}

// link round, elementwise, one 32-w slab per block:
// s_next[b,i,w] = relu(sig(s_prev[b,w,i])*u[b,w,i,:] + b_l1) . W_l2 + b_l2
__global__ __launch_bounds__(256)
void k_linkE(const bf16* ub, const float* s_prev, const void* b_l1,
             const void* W_l2, const void* b_l2,
             const int* hn, const int* on, float* s_next, const int* dflag)
{
  bool bf = (*dflag != 0);
  int b = blockIdx.z, i = blockIdx.y, w0 = blockIdx.x*32;
  int valid = hn[b] + on[b];
  if (i >= valid || w0 >= valid) return;
  int t = threadIdx.x;
  __shared__ float bl1s[M_], wl2s[M_];
  if (t < M_){ bl1s[t] = ldr(b_l1, t, bf); wl2s[t] = ldr(W_l2, t, bf); }
  __syncthreads();
  int e = t>>3, seg = t&7;     // 32 edges, 8 lanes/edge, 16 feats/lane
  int w = w0 + e;
  if (w >= valid) return;
  float sg = sigm(s_prev[((size_t)(b*N_)+w)*N_ + i]);
  const short8* up = (const short8*)(ub + (((size_t)(b*N_)+w)*N_ + i)*M_ + seg*16);
  short8 v0 = up[0], v1 = up[1];
  float p = 0.f;
  #pragma unroll
  for (int q=0;q<8;q++){
    int k = seg*16 + q;
    p += fmaxf(sg*s2f(v0[q]) + bl1s[k], 0.f) * wl2s[k];
  }
  #pragma unroll
  for (int q=0;q<8;q++){
    int k = seg*16 + 8 + q;
    p += fmaxf(sg*s2f(v1[q]) + bl1s[k], 0.f) * wl2s[k];
  }
  p += __shfl_down(p, 4, 8);
  p += __shfl_down(p, 2, 8);
  p += __shfl_down(p, 1, 8);
  if (seg==0) s_next[((size_t)(b*N_)+i)*N_ + w] = p + ldr(b_l2, 0, bf);
}

// final: pred_adj = s2 ; m_sum = sum_w sig(s2)*mraw ; GRU ; readout
__global__ __launch_bounds__(128)
void k_final(const bf16* mraw, const float* s2, const float* nf,
             const bf16* tWih, const void* b_ih,
             const bf16* tWhh, const void* b_hh,
             const bf16* tWro, const void* b_ro,
             const int* hn, const int* on, void* out, const int* dflag)
{
  bool bf = (*dflag != 0);
  int i = blockIdx.x, b = blockIdx.y;
  int valid = hn[b] + on[b];
  if (i >= valid) return;
  int t = threadIdx.x;  // 128
  __shared__ float sgs[N_];
  __shared__ float xsh[M_], hsh[M_], hns[M_];
  const float* srow = s2 + ((size_t)(b*N_)+i)*N_;
  size_t adj = ((size_t)(b*N_)+i)*N_;
  for (int w=t; w<N_; w+=128){
    if (w < valid){
      float v = srow[w];
      str(out, adj + w, v, bf);
      sgs[w] = sigm(v);
    } else sgs[w] = 0.f;
  }
  __syncthreads();
  const short* mrow = (const short*)mraw + (((size_t)(b*N_)+i)*N_)*M_;
  float acc = 0.f;
  for (int w=0; w<valid; w++) acc += sgs[w]*s2f(mrow[(size_t)w*M_ + t]);
  xsh[t] = acc;
  hsh[t] = nf[((size_t)(b*N_)+i)*M_ + t];
  __syncthreads();
  float gi[3], gh[3];
  #pragma unroll
  for (int g=0; g<3; g++){
    int o = g*M_ + t;
    float a = ldr(b_ih, o, bf), c = ldr(b_hh, o, bf);
    const short8* wi = (const short8*)(tWih + (size_t)o*M_);
    const short8* wh = (const short8*)(tWhh + (size_t)o*M_);
    #pragma unroll 4
    for (int k8=0;k8<16;k8++){
      a += dot8(wi[k8], &xsh[k8*8]);
      c += dot8(wh[k8], &hsh[k8*8]);
    }
    gi[g] = a; gh[g] = c;
  }
  float r  = sigm(gi[0] + gh[0]);
  float z  = sigm(gi[1] + gh[1]);
  float nn = tanhf(gi[2] + r*gh[2]);
  float hnew = (1.f - z)*nn + z*hsh[t];
  hns[t] = hnew;
  __syncthreads();
  size_t lab = (size_t)ADJ_SZ + ((size_t)(b*N_)+i)*CL_;
  for (int cls=t; cls<CL_; cls+=128){
    float a = ldr(b_ro, cls, bf);
    const short8* wr = (const short8*)(tWro + (size_t)cls*M_);
    #pragma unroll 4
    for (int k8=0;k8<16;k8++) a += dot8(wr[k8], &hns[k8*8]);
    str(out, lab + cls, a, bf);
  }
}

extern "C" void kernel_launch(void* const* d_in, const int* in_sizes, int n_in,
                              void* d_out, int out_size, void* d_ws, size_t ws_size,
                              hipStream_t stream)
{
  char* ws = (char*)d_ws;

  const void* edgef = d_in[0];
  const void* nodef = d_in[1];
  const int*  hn    = (const int*)d_in[4];
  const int*  on    = (const int*)d_in[5];
  const void* W_er  = d_in[6];  const void* b_er  = d_in[7];
  const void* W_nr  = d_in[8];  const void* b_nr  = d_in[9];
  const void* W_l1  = d_in[10]; const void* b_l1  = d_in[11];
  const void* W_l2  = d_in[12]; const void* b_l2  = d_in[13];
  const void* W_msg = d_in[14]; const void* b_msg = d_in[15];
  const void* W_ih  = d_in[16]; const void* b_ih  = d_in[17];
  const void* W_hh  = d_in[18]; const void* b_hh  = d_in[19];
  const void* W_ro  = d_in[20]; const void* b_ro  = d_in[21];

  bf16*  mraw   = (bf16*) (ws);                 // [0, 64 MiB)
  bf16*  ub     = (bf16*) (ws + 67108864);      // [64, 128 MiB)
  float* s_a    = (float*)(ws + 134217728);     // 1 MiB
  float* s_b    = (float*)(ws + 135266304);     // 1 MiB
  float* nf     = (float*)(ws + 136314880);     // 512 KiB
  float* cb     = (float*)(ws + 136839168);     // 512 KiB
  bf16*  pWer   = (bf16*) (ws + 137363456);     // 64 KiB
  bf16*  pWmsgB = (bf16*) (ws + 137428992);     // 32 KiB
  bf16*  pWl1   = (bf16*) (ws + 137461760);     // 32 KiB
  bf16*  tWnr   = (bf16*) (ws + 137494528);     // 64 KiB
  bf16*  tWmsgT = (bf16*) (ws + 137560064);     // 32 KiB
  bf16*  tWih   = (bf16*) (ws + 137592832);     // 96 KiB
  bf16*  tWhh   = (bf16*) (ws + 137691136);     // 96 KiB
  bf16*  tWro   = (bf16*) (ws + 137789440);     // 150 KiB
  int*   dflag  = (int*)  (ws + 137943040);

  k_detect<<<1, 64, 0, stream>>>((const unsigned short*)d_in[0], dflag);

  int nzb = (out_size + 255) / 256;
  k_prep<<<nzb + 32 + 876, 256, 0, stream>>>(
      W_er, W_msg, W_l1, W_nr, W_ih, W_hh, W_ro,
      pWer, pWmsgB, pWl1, tWnr, tWmsgT, tWih, tWhh, tWro,
      d_out, out_size, dflag);

  k_nf_c<<<B_*N_, 128, 0, stream>>>(nodef, tWnr, b_nr, tWmsgT, b_msg, nf, cb, dflag);

  dim3 g2(N_/32, N_, B_);
  k_r0<<<g2, 256, 0, stream>>>(edgef, pWer, b_er, pWmsgB, cb, pWl1,
                               b_l1, W_l2, b_l2, hn, on, mraw, ub, s_a, dflag);

  k_linkE<<<g2, 256, 0, stream>>>(ub, s_a, b_l1, W_l2, b_l2, hn, on, s_b, dflag);
  k_linkE<<<g2, 256, 0, stream>>>(ub, s_b, b_l1, W_l2, b_l2, hn, on, s_a, dflag);

  dim3 gl(N_, B_);
  k_final<<<gl, 128, 0, stream>>>(mraw, s_a, nf, tWih, b_ih, tWhh, b_hh,
                                  tWro, b_ro, hn, on, d_out, dflag);
}